// Round 7
// baseline (351.106 us; speedup 1.0000x reference)
//
#include <hip/hip_runtime.h>
#include <math.h>

// ---------------------------------------------------------------------------
// B=64 graphs, NN=133 nodes. 8 plain launches:
//  K1 prep_emb : blocks<399 -> emb GEMM tiles; blocks>=399 -> sparse prep
//  K2 gemm1    : t1 = h0@gc1_w                     (bC -> bA, ld 256)
//  K3 spmm1    : y1 = relu(A@t1+b1)                (bA -> bB, ld 256)
//  K4 gemm2+P  : t2 = pool(y1)@gc2_w  (A-gather)   (bB -> bA, ld 128)
//  K5 spmm2    : y2 = relu(A@t2+b2)                (bA -> bC, ld 128)
//  K6 gemm3+P  : t3 = pool(y2)@gc3_w  (A-gather)   (bC -> bA, ld 76)
//  K7 spmm3    : y3 = relu(A@t3+b3)                (bA -> bB, ld 76)
//  K8 tail+P   : p3 on the fly -> gc4 -> fc1 -> fin -> sigmoid
// Pool fused into consumers' load paths (pool = col-independent gather-max of
// post-relu y >= 0, init 0 exact). Sparse lists per row: front = a>1e-5
// (spmm+pool), back = 0<a<=1e-5 (spmm only).
// ---------------------------------------------------------------------------

#define NN 133
#define NPAIR 64

// Gather-max of float4 over front neighbors (the fused pool).
__device__ __forceinline__ float4 pgather(
    const float* __restrict__ Y, size_t robase, int ldy, int kk,
    const float2* __restrict__ pbp, int cx)
{
    float4 g = make_float4(0.f, 0.f, 0.f, 0.f);
    int q = 0;
    for (; q + 2 <= cx; q += 2) {
        int j0 = __float_as_int(pbp[q].y), j1 = __float_as_int(pbp[q + 1].y);
        float4 v0 = *reinterpret_cast<const float4*>(Y + robase + (size_t)j0 * ldy + kk);
        float4 v1 = *reinterpret_cast<const float4*>(Y + robase + (size_t)j1 * ldy + kk);
        g.x = fmaxf(g.x, fmaxf(v0.x, v1.x));
        g.y = fmaxf(g.y, fmaxf(v0.y, v1.y));
        g.z = fmaxf(g.z, fmaxf(v0.z, v1.z));
        g.w = fmaxf(g.w, fmaxf(v0.w, v1.w));
    }
    if (q < cx) {
        int j = __float_as_int(pbp[q].y);
        float4 v = *reinterpret_cast<const float4*>(Y + robase + (size_t)j * ldy + kk);
        g.x = fmaxf(g.x, v.x); g.y = fmaxf(g.y, v.y);
        g.z = fmaxf(g.z, v.z); g.w = fmaxf(g.w, v.w);
    }
    return g;
}

// ------------- GEMM core: one 64x64 tile, prefetch-pipelined ----------------
// POOLA: A[r,k] = max over front-nbrs j of Y[b,j,k] (fused pooling gather).
template<int POOLA, int VECA, int VECB, int RELU, int BIAS>
__device__ __forceinline__ void gemm_tile_core(
    const float* __restrict__ A, int lda, int K,
    const float* __restrict__ W, int N,
    const float* __restrict__ bias,
    const float2* __restrict__ pairs, const int2* __restrict__ cnts,
    float* __restrict__ C, int ldc, int padN,
    int m0, int n0, float (*As)[68], float (*Bs)[68], int tid)
{
    const int la_m = tid >> 2, la_k = (tid & 3) * 4;   // A: 64 rows x 4 float4
    const int lb_k = tid >> 4, lb_n = (tid & 15) * 4;  // B: 16 k-rows x 16 f4
    const int tx = tid & 15, ty = tid >> 4;

    // fused-pool thread context (row is fixed per thread)
    const int r = m0 + la_m;
    size_t robase = 0; const float2* pbp = nullptr; int cx = 0;
    if (POOLA) {
        robase = (size_t)(r / NN) * NN * lda;
        pbp = pairs + (size_t)r * NPAIR;
        cx = cnts[r].x;
    }

    float pa[4], pb[4];
    if (POOLA) {
        float4 g = pgather(A, robase, lda, la_k, pbp, cx);
        pa[0] = g.x; pa[1] = g.y; pa[2] = g.z; pa[3] = g.w;
    } else if (VECA) {
        float4 v = *reinterpret_cast<const float4*>(
            A + (size_t)r * lda + la_k);
        pa[0] = v.x; pa[1] = v.y; pa[2] = v.z; pa[3] = v.w;
    } else {
#pragma unroll
        for (int j = 0; j < 4; ++j) {
            int gk = la_k + j;
            pa[j] = (gk < K) ? A[(size_t)r * lda + gk] : 0.f;
        }
    }
    if (VECB) {
        if (lb_k < K) {
            float4 v = *reinterpret_cast<const float4*>(
                W + (size_t)lb_k * N + n0 + lb_n);
            pb[0] = v.x; pb[1] = v.y; pb[2] = v.z; pb[3] = v.w;
        } else { pb[0] = pb[1] = pb[2] = pb[3] = 0.f; }
    } else {
#pragma unroll
        for (int j = 0; j < 4; ++j) {
            int gn = n0 + lb_n + j;
            pb[j] = (lb_k < K && gn < N) ? W[(size_t)lb_k * N + gn] : 0.f;
        }
    }

    float acc[4][4] = {};
    for (int k0 = 0; k0 < K; k0 += 16) {
        __syncthreads();
#pragma unroll
        for (int j = 0; j < 4; ++j) As[la_k + j][la_m] = pa[j];
        *reinterpret_cast<float4*>(&Bs[lb_k][lb_n]) =
            make_float4(pb[0], pb[1], pb[2], pb[3]);
        __syncthreads();
        const int kn = k0 + 16;
        if (kn < K) {   // prefetch next k-tile (overlaps FMA block)
            if (POOLA) {
                float4 g = pgather(A, robase, lda, kn + la_k, pbp, cx);
                pa[0] = g.x; pa[1] = g.y; pa[2] = g.z; pa[3] = g.w;
            } else if (VECA) {
                float4 v = *reinterpret_cast<const float4*>(
                    A + (size_t)r * lda + kn + la_k);
                pa[0] = v.x; pa[1] = v.y; pa[2] = v.z; pa[3] = v.w;
            } else {
#pragma unroll
                for (int j = 0; j < 4; ++j) {
                    int gk = kn + la_k + j;
                    pa[j] = (gk < K) ? A[(size_t)r * lda + gk] : 0.f;
                }
            }
            int gk = kn + lb_k;
            if (VECB) {
                if (gk < K) {
                    float4 v = *reinterpret_cast<const float4*>(
                        W + (size_t)gk * N + n0 + lb_n);
                    pb[0] = v.x; pb[1] = v.y; pb[2] = v.z; pb[3] = v.w;
                } else { pb[0] = pb[1] = pb[2] = pb[3] = 0.f; }
            } else {
#pragma unroll
                for (int j = 0; j < 4; ++j) {
                    int gn = n0 + lb_n + j;
                    pb[j] = (gk < K && gn < N) ? W[(size_t)gk * N + gn] : 0.f;
                }
            }
        }
#pragma unroll
        for (int k = 0; k < 16; ++k) {
            float4 av = *reinterpret_cast<const float4*>(&As[k][ty * 4]);
            float4 bv = *reinterpret_cast<const float4*>(&Bs[k][tx * 4]);
            float a[4] = {av.x, av.y, av.z, av.w};
            float b[4] = {bv.x, bv.y, bv.z, bv.w};
#pragma unroll
            for (int i = 0; i < 4; ++i)
#pragma unroll
                for (int j = 0; j < 4; ++j)
                    acc[i][j] = fmaf(a[i], b[j], acc[i][j]);
        }
    }
#pragma unroll
    for (int i = 0; i < 4; ++i) {
        int gm = m0 + ty * 4 + i;
#pragma unroll
        for (int j = 0; j < 4; ++j) {
            int gn = n0 + tx * 4 + j;
            if (gn < padN) {
                float v = 0.f;
                if (gn < N) {
                    v = acc[i][j];
                    if (BIAS) v += bias[gn];
                    if (RELU) v = fmaxf(v, 0.f);
                }
                C[(size_t)gm * ldc + gn] = v;
            }
        }
    }
}

template<int POOLA, int VECA, int VECB>
__global__ __launch_bounds__(256)
void gemm_k(const float* __restrict__ A, int lda, int K,
            const float* __restrict__ W, int N,
            const float2* __restrict__ pairs, const int2* __restrict__ cnts,
            float* __restrict__ C, int ldc, int padN, int tiles_n)
{
    __shared__ float As[16][68];
    __shared__ float Bs[16][68];
    const int t = blockIdx.x;
    gemm_tile_core<POOLA, VECA, VECB, 0, 0>(
        A, lda, K, W, N, nullptr, pairs, cnts, C, ldc, padN,
        (t / tiles_n) * 64, (t % tiles_n) * 64, As, Bs, threadIdx.x);
}

// -------- K1: emb GEMM tiles (blocks<399) + sparse prep (blocks>=399) -------
__global__ __launch_bounds__(256)
void prep_emb_k(const float* __restrict__ x,
                const float* __restrict__ emb_w, const float* __restrict__ emb_b,
                const float* __restrict__ adj,
                float2* __restrict__ pairs, int2* __restrict__ cnts,
                float* __restrict__ h0)
{
    __shared__ float As[16][68];
    __shared__ float Bs[16][68];
    __shared__ int c0s[NN], c1s[NN];
    const int tid = threadIdx.x;
    if (blockIdx.x < 399) {
        const int t = blockIdx.x;
        gemm_tile_core<0, 0, 0, 1, 1>(
            x, 75, 75, emb_w, 150, emb_b, nullptr, nullptr, h0, 152, 152,
            (t / 3) * 64, (t % 3) * 64, As, Bs, tid);
    } else {
        const int b = blockIdx.x - 399;
        for (int i = tid; i < NN; i += 256) { c0s[i] = 0; c1s[i] = 0; }
        __syncthreads();
        const float* adjb = adj + (size_t)b * NN * NN;
        float2* pbg = pairs + (size_t)b * NN * NPAIR;
        for (int q = tid; q < NN * NN; q += 256) {
            int i = q / NN, j = q - i * NN;
            float a = adjb[q];
            if (a > 1e-5f) {
                int s = atomicAdd(&c0s[i], 1);
                pbg[i * NPAIR + s] = make_float2(a, __int_as_float(j));
            } else if (a > 0.f) {
                int s = atomicAdd(&c1s[i], 1);
                pbg[i * NPAIR + (NPAIR - 1) - s] = make_float2(a, __int_as_float(j));
            }
        }
        __syncthreads();
        for (int i = tid; i < NN; i += 256)
            cnts[b * NN + i] = make_int2(c0s[i], c1s[i]);
    }
}

// -------- spmm: y[r,col] = relu(sum_j a_rj * t[j,col] + bias[col]) ----------
// 1024 threads = 16 waves; one wave per (global row r, 64-col chunk).
__global__ __launch_bounds__(1024)
void spmm_k(const float* __restrict__ t, int ld, int N,
            const float* __restrict__ bias,
            const float2* __restrict__ pairs, const int2* __restrict__ cnts,
            float* __restrict__ y, int chsh)
{
    const int wave = threadIdx.x >> 6, lane = threadIdx.x & 63;
    const int item = blockIdx.x * 16 + wave;
    const int r = item >> chsh, ch = item & ((1 << chsh) - 1);
    const int b = r / NN;
    const int col0 = (ch << 6) + lane;
    const int col = min(col0, N - 1);           // clamp for safe loads
    const float2* pb = pairs + (size_t)r * NPAIR;
    const int2 c = cnts[r];
    const float* tb = t + (size_t)b * NN * ld;

    float s0 = 0.f, s1 = 0.f, s2 = 0.f, s3 = 0.f;
    int q = 0;
    for (; q + 4 <= c.x; q += 4) {              // 4 gathers in flight
        float2 f0 = pb[q], f1 = pb[q + 1], f2 = pb[q + 2], f3 = pb[q + 3];
        s0 = fmaf(f0.x, tb[(size_t)__float_as_int(f0.y) * ld + col], s0);
        s1 = fmaf(f1.x, tb[(size_t)__float_as_int(f1.y) * ld + col], s1);
        s2 = fmaf(f2.x, tb[(size_t)__float_as_int(f2.y) * ld + col], s2);
        s3 = fmaf(f3.x, tb[(size_t)__float_as_int(f3.y) * ld + col], s3);
    }
    for (; q < c.x; ++q) {
        float2 f = pb[q];
        s0 = fmaf(f.x, tb[(size_t)__float_as_int(f.y) * ld + col], s0);
    }
    for (int u = 0; u < c.y; ++u) {             // tiny-weight tail (spmm only)
        float2 f = pb[(NPAIR - 1) - u];
        s0 = fmaf(f.x, tb[(size_t)__float_as_int(f.y) * ld + col], s0);
    }
    if (col0 < N) {
        float s = (s0 + s1) + (s2 + s3) + bias[col0];
        y[(size_t)r * ld + col0] = fmaxf(s, 0.f);
    }
}

// -------- tail: fused pool3 -> gc4 -> sparse A -> fc1 -> fin -> sigmoid -----
__global__ __launch_bounds__(512)
void tail_k(const float* __restrict__ y3,   // ld 76, 75 valid cols
            const float2* __restrict__ pairs, const int2* __restrict__ cnts,
            const float* __restrict__ gc4_w, const float* __restrict__ gc4_b,
            const float* __restrict__ fc1_w, const float* __restrict__ fc1_b,
            const float* __restrict__ fin_w, const float* __restrict__ fin_b,
            float* __restrict__ out)
{
    const int b = blockIdx.x, tid = threadIdx.x;
    const int wave = tid >> 6, lane = tid & 63;
    __shared__ float t4S[NN], y4S[NN], rS[3];
    const float* yb = y3 + (size_t)b * NN * 76;

    // t4[i] = dot(pool(y3)[i, 0:75], gc4_w): lane covers col=lane (+ col=64+
    // lane for lane<11); wave-reduce the partial dot. (y3 >= 0, init 0 exact.)
    const float gw0 = gc4_w[lane];                        // lane<=63<75 valid
    const float gw1 = (lane < 11) ? gc4_w[64 + lane] : 0.f;
    const int c2 = 64 + min(lane, 10);                    // safe 2nd col
    for (int i = wave; i < NN; i += 8) {
        const float2* pb = pairs + ((size_t)b * NN + i) * NPAIR;
        const int cx = cnts[b * NN + i].x;
        float m0 = 0.f, m1 = 0.f;
        for (int q = 0; q < cx; ++q) {
            const float* row = yb + (size_t)__float_as_int(pb[q].y) * 76;
            m0 = fmaxf(m0, row[lane]);
            m1 = fmaxf(m1, row[c2]);
        }
        float v = m0 * gw0 + m1 * gw1;
#pragma unroll
        for (int off = 32; off; off >>= 1) v += __shfl_xor(v, off, 64);
        if (lane == 0) t4S[i] = v;
    }
    __syncthreads();
    if (tid < NN) {
        const float2* pb = pairs + ((size_t)b * NN + tid) * NPAIR;
        int2 c = cnts[b * NN + tid];
        float s = gc4_b[0];
        for (int q = 0; q < c.x; ++q) {
            float2 f = pb[q];
            s = fmaf(f.x, t4S[__float_as_int(f.y)], s);
        }
        for (int q = 0; q < c.y; ++q) {
            float2 f = pb[(NPAIR - 1) - q];
            s = fmaf(f.x, t4S[__float_as_int(f.y)], s);
        }
        y4S[tid] = fmaxf(s, 0.f);
    }
    __syncthreads();
    if (tid < 3) {
        float s = fc1_b[tid];
        for (int j = 0; j < 132; ++j)
            s = fmaf(y4S[1 + j], fc1_w[j * 3 + tid], s);
        rS[tid] = s;
    }
    __syncthreads();
    if (tid == 0) {
        float z = fin_b[0] + y4S[0] * fin_w[0] + rS[0] * fin_w[1]
                + rS[1] * fin_w[2] + rS[2] * fin_w[3];
        out[b] = 1.f / (1.f + expf(-z));
    }
}

extern "C" void kernel_launch(void* const* d_in, const int* in_sizes, int n_in,
                              void* d_out, int out_size, void* d_ws, size_t ws_size,
                              hipStream_t stream)
{
    const float* x     = (const float*)d_in[0];
    const float* adj   = (const float*)d_in[1];
    const float* emb_w = (const float*)d_in[2];
    const float* emb_b = (const float*)d_in[3];
    const float* gc1_w = (const float*)d_in[4];
    const float* gc1_b = (const float*)d_in[5];
    const float* gc2_w = (const float*)d_in[6];
    const float* gc2_b = (const float*)d_in[7];
    const float* gc3_w = (const float*)d_in[8];
    const float* gc3_b = (const float*)d_in[9];
    const float* gc4_w = (const float*)d_in[10];
    const float* gc4_b = (const float*)d_in[11];
    const float* fc1_w = (const float*)d_in[12];
    const float* fc1_b = (const float*)d_in[13];
    const float* fin_w = (const float*)d_in[14];
    const float* fin_b = (const float*)d_in[15];
    float* out = (float*)d_out;

    // ws: pairs 4.36MB | cnts 68KB | bA 8.72MB | bB 8.72MB | bC 8.72MB
    const long MR = 64L * NN;                    // 8512
    float2* pairs = (float2*)d_ws;
    int2*   cnts  = (int2*)(pairs + MR * NPAIR);
    float*  bA    = (float*)(cnts + MR);
    float*  bB    = bA + MR * 256;
    float*  bC    = bB + MR * 256;

    // K1: emb GEMM (399 tiles) -> bC (h0, ld 152) + sparse prep (64 graphs)
    prep_emb_k<<<463, 256, 0, stream>>>(x, emb_w, emb_b, adj, pairs, cnts, bC);
    // K2: t1 = h0 @ gc1_w -> bA ld 256
    gemm_k<0, 1, 1><<<532, 256, 0, stream>>>(
        bC, 152, 150, gc1_w, 256, nullptr, nullptr, bA, 256, 256, 4);
    // K3: y1 -> bB ld 256   (34048 items / 16 waves)
    spmm_k<<<2128, 1024, 0, stream>>>(bA, 256, 256, gc1_b, pairs, cnts, bB, 2);
    // K4: t2 = pool(y1) @ gc2_w -> bA ld 128  (fused pool gather on A)
    gemm_k<1, 1, 1><<<266, 256, 0, stream>>>(
        bB, 256, 256, gc2_w, 128, pairs, cnts, bA, 128, 128, 2);
    // K5: y2 -> bC ld 128   (17024 items / 16)
    spmm_k<<<1064, 1024, 0, stream>>>(bA, 128, 128, gc2_b, pairs, cnts, bC, 1);
    // K6: t3 = pool(y2) @ gc3_w -> bA ld 76
    gemm_k<1, 1, 0><<<266, 256, 0, stream>>>(
        bC, 128, 128, gc3_w, 75, pairs, cnts, bA, 76, 76, 2);
    // K7: y3 -> bB ld 76
    spmm_k<<<1064, 1024, 0, stream>>>(bA, 76, 75, gc3_b, pairs, cnts, bB, 1);
    // K8: tail (+fused pool3)
    tail_k<<<64, 512, 0, stream>>>(bB, pairs, cnts, gc4_w, gc4_b,
                                   fc1_w, fc1_b, fin_w, fin_b, out);
}